// Round 1
// baseline (263.301 us; speedup 1.0000x reference)
//
#include <hip/hip_runtime.h>

// CCQC quantum-circuit classifier, fused single-kernel state-vector sim.
// State layout: one wave (64 lanes) per batch element; amplitude index
// j = k*64 + lane (k in [0,16)). Wire i (MSB-first) <-> bit b = 9-i of j.
// b in [6,9] -> k-bit (in-lane register pair); b in [0,5] -> lane bit (shfl_xor).

namespace {

struct c2 { float r, i; };
struct m2c { c2 a00, a01, a10, a11; };

__device__ __forceinline__ c2 cmul(c2 x, c2 y) { return {x.r*y.r - x.i*y.i, x.r*y.i + x.i*y.r}; }
__device__ __forceinline__ c2 cadd(c2 x, c2 y) { return {x.r + y.r, x.i + y.i}; }
__device__ __forceinline__ m2c mmul(m2c A, m2c B) {
  m2c C;
  C.a00 = cadd(cmul(A.a00, B.a00), cmul(A.a01, B.a10));
  C.a01 = cadd(cmul(A.a00, B.a01), cmul(A.a01, B.a11));
  C.a10 = cadd(cmul(A.a10, B.a00), cmul(A.a11, B.a10));
  C.a11 = cadd(cmul(A.a10, B.a01), cmul(A.a11, B.a11));
  return C;
}
__device__ __forceinline__ m2c mrx(float t) {
  float c = cosf(0.5f * t), s = sinf(0.5f * t);
  return { {c, 0.f}, {0.f, -s}, {0.f, -s}, {c, 0.f} };
}
__device__ __forceinline__ m2c mrz(float t) {
  float c = cosf(0.5f * t), s = sinf(0.5f * t);
  return { {c, -s}, {0.f, 0.f}, {0.f, 0.f}, {c, s} };
}

// Fused gate matrices -> ws. Layout: per layer d (21 matrices of 8 floats):
//   [0..9]  U1[i]  = RX(w[d,i,2]) * RZ(w[d,i,1]) * RX(w[d,i,0])
//   [10..19] CU[i] = RX(w[d,i,4]) * RZ(w[d,i,3])   (ctrl = (i+r)%10)
//   [20]    U0     = RZ(w2[d]) * RX(w1[d])
__global__ void make_mats(const float* __restrict__ w, const float* __restrict__ w1,
                          const float* __restrict__ w2, float* __restrict__ mats) {
  int t = threadIdx.x;
  m2c U{}; int idx = -1;
  if (t < 50) {
    int d = t / 10, i = t % 10;
    const float* p = w + (d * 10 + i) * 5;
    U = mmul(mrx(p[2]), mmul(mrz(p[1]), mrx(p[0])));
    idx = d * 21 + i;
  } else if (t < 100) {
    int s = t - 50; int d = s / 10, i = s % 10;
    const float* p = w + (d * 10 + i) * 5;
    U = mmul(mrx(p[4]), mrz(p[3]));
    idx = d * 21 + 10 + i;
  } else if (t < 105) {
    int d = t - 100;
    U = mmul(mrz(w2[d]), mrx(w1[d]));
    idx = d * 21 + 20;
  }
  if (idx >= 0) {
    float* o = mats + idx * 8;
    o[0] = U.a00.r; o[1] = U.a00.i; o[2] = U.a01.r; o[3] = U.a01.i;
    o[4] = U.a10.r; o[5] = U.a10.i; o[6] = U.a11.r; o[7] = U.a11.i;
  }
}

struct Mat8 { float u00r, u00i, u01r, u01i, u10r, u10i, u11r, u11i; };

__device__ __forceinline__ Mat8 ldmat(const float* __restrict__ mats, int idx) {
  const float4* p = reinterpret_cast<const float4*>(mats + idx * 8);
  float4 a = p[0], b = p[1];
  return {a.x, a.y, a.z, a.w, b.x, b.y, b.z, b.w};
}

// Single-qubit gate, target bit is a k-bit (kb = b-6).
__device__ __forceinline__ void ap1q_local(float (&sr)[16], float (&si)[16], const int kb,
                                           const Mat8 m) {
  const int tm = 1 << kb;
  #pragma unroll
  for (int k0 = 0; k0 < 16; ++k0) {
    if (k0 & tm) continue;
    const int k1 = k0 | tm;
    const float ar = sr[k0], ai = si[k0], br = sr[k1], bi = si[k1];
    sr[k0] = m.u00r*ar - m.u00i*ai + m.u01r*br - m.u01i*bi;
    si[k0] = m.u00r*ai + m.u00i*ar + m.u01r*bi + m.u01i*br;
    sr[k1] = m.u10r*ar - m.u10i*ai + m.u11r*br - m.u11i*bi;
    si[k1] = m.u10r*ai + m.u10i*ar + m.u11r*bi + m.u11i*br;
  }
}

// Single-qubit gate, target bit is a lane bit (lm = 1<<b).
__device__ __forceinline__ void ap1q_xlane(float (&sr)[16], float (&si)[16],
                                           const int lane, const int lm, const Mat8 m) {
  const bool hi = (lane & lm) != 0;
  const float r0r = hi ? m.u10r : m.u00r, r0i = hi ? m.u10i : m.u00i;
  const float r1r = hi ? m.u11r : m.u01r, r1i = hi ? m.u11i : m.u01i;
  #pragma unroll
  for (int k = 0; k < 16; ++k) {
    const float pr = __shfl_xor(sr[k], lm, 64);
    const float pi = __shfl_xor(si[k], lm, 64);
    const float ar = hi ? pr : sr[k], ai = hi ? pi : si[k];
    const float br = hi ? sr[k] : pr, bi = hi ? si[k] : pi;
    sr[k] = r0r*ar - r0i*ai + r1r*br - r1i*bi;
    si[k] = r0r*ai + r0i*ar + r1r*bi + r1i*br;
  }
}

// Controlled gate, target bit is a k-bit (kb = bt-6); ctrl bit bc (j-bit index).
__device__ __forceinline__ void apc_local(float (&sr)[16], float (&si)[16],
                                          const int lane, const int bc, const int kb,
                                          const Mat8 m) {
  const int tm = 1 << kb;
  if (bc >= 6) {
    const int cm = 1 << (bc - 6);
    #pragma unroll
    for (int k0 = 0; k0 < 16; ++k0) {
      if ((k0 & tm) || !(k0 & cm)) continue;
      const int k1 = k0 | tm;
      const float ar = sr[k0], ai = si[k0], br = sr[k1], bi = si[k1];
      sr[k0] = m.u00r*ar - m.u00i*ai + m.u01r*br - m.u01i*bi;
      si[k0] = m.u00r*ai + m.u00i*ar + m.u01r*bi + m.u01i*br;
      sr[k1] = m.u10r*ar - m.u10i*ai + m.u11r*br - m.u11i*bi;
      si[k1] = m.u10r*ai + m.u10i*ar + m.u11r*bi + m.u11i*br;
    }
  } else {
    const bool cl = ((lane >> bc) & 1) != 0;
    #pragma unroll
    for (int k0 = 0; k0 < 16; ++k0) {
      if (k0 & tm) continue;
      const int k1 = k0 | tm;
      const float ar = sr[k0], ai = si[k0], br = sr[k1], bi = si[k1];
      const float n0r = m.u00r*ar - m.u00i*ai + m.u01r*br - m.u01i*bi;
      const float n0i = m.u00r*ai + m.u00i*ar + m.u01r*bi + m.u01i*br;
      const float n1r = m.u10r*ar - m.u10i*ai + m.u11r*br - m.u11i*bi;
      const float n1i = m.u10r*ai + m.u10i*ar + m.u11r*bi + m.u11i*br;
      sr[k0] = cl ? n0r : ar; si[k0] = cl ? n0i : ai;
      sr[k1] = cl ? n1r : br; si[k1] = cl ? n1i : bi;
    }
  }
}

// Controlled gate, target bit is a lane bit (lm = 1<<bt); ctrl bit bc.
__device__ __forceinline__ void apc_xlane(float (&sr)[16], float (&si)[16],
                                          const int lane, const int bc, const int lm,
                                          const Mat8 m) {
  const bool hi = (lane & lm) != 0;
  const float r0r = hi ? m.u10r : m.u00r, r0i = hi ? m.u10i : m.u00i;
  const float r1r = hi ? m.u11r : m.u01r, r1i = hi ? m.u11i : m.u01i;
  if (bc >= 6) {
    const int cm = 1 << (bc - 6);
    #pragma unroll
    for (int k = 0; k < 16; ++k) {
      if (!(k & cm)) continue;   // ctrl bit in k: only these amps touched
      const float pr = __shfl_xor(sr[k], lm, 64);
      const float pi = __shfl_xor(si[k], lm, 64);
      const float ar = hi ? pr : sr[k], ai = hi ? pi : si[k];
      const float br = hi ? sr[k] : pr, bi = hi ? si[k] : pi;
      sr[k] = r0r*ar - r0i*ai + r1r*br - r1i*bi;
      si[k] = r0r*ai + r0i*ar + r1r*bi + r1i*br;
    }
  } else {
    const bool cl = ((lane >> bc) & 1) != 0;   // lane-level ctrl, predicated write
    #pragma unroll
    for (int k = 0; k < 16; ++k) {
      const float pr = __shfl_xor(sr[k], lm, 64);
      const float pi = __shfl_xor(si[k], lm, 64);
      const float ar = hi ? pr : sr[k], ai = hi ? pi : si[k];
      const float br = hi ? sr[k] : pr, bi = hi ? si[k] : pi;
      const float nr = r0r*ar - r0i*ai + r1r*br - r1i*bi;
      const float ni = r0r*ai + r0i*ar + r1r*bi + r1i*br;
      sr[k] = cl ? nr : sr[k];
      si[k] = cl ? ni : si[k];
    }
  }
}

__global__ __launch_bounds__(256) void qsim(const float* __restrict__ x,
                                            const int* __restrict__ y,
                                            const float* __restrict__ mats,
                                            float* __restrict__ partials) {
  const int lane = threadIdx.x & 63;
  const int wave = threadIdx.x >> 6;
  const int b = blockIdx.x * 4 + wave;
  const int yv = y[b];

  float sr[16], si[16];
  float ss = 0.f;
  #pragma unroll
  for (int k = 0; k < 16; ++k) {
    const int j = k * 64 + lane;
    float v = 0.f;
    if (j < 784) v = x[(size_t)b * 784 + j];
    sr[k] = v; si[k] = 0.f; ss += v * v;
  }
  #pragma unroll
  for (int mm = 1; mm < 64; mm <<= 1) ss += __shfl_xor(ss, mm, 64);
  const float rn = rsqrtf(ss);
  #pragma unroll
  for (int k = 0; k < 16; ++k) sr[k] *= rn;

  #pragma unroll
  for (int d = 0; d < 5; ++d) {
    #pragma unroll
    for (int i = 0; i < 10; ++i) {
      const Mat8 m = ldmat(mats, d * 21 + i);
      const int bt = 9 - i;
      if (bt >= 6) ap1q_local(sr, si, bt - 6, m);
      else         ap1q_xlane(sr, si, lane, 1 << bt, m);
    }
    const int r = (d & 1) ? 3 : 1;
    #pragma unroll
    for (int i = 0; i < 10; ++i) {
      const int c = (i + r) % 10;
      const Mat8 m = ldmat(mats, d * 21 + 10 + i);
      const int bc = 9 - c, bt = 9 - i;
      if (bt >= 6) apc_local(sr, si, lane, bc, bt - 6, m);
      else         apc_xlane(sr, si, lane, bc, 1 << bt, m);
    }
    const Mat8 m = ldmat(mats, d * 21 + 20);
    ap1q_local(sr, si, 3, m);   // wire 0 -> j bit 9 -> k bit 3
  }

  // expz for wire 0 (k bit 3) and wire 1 (k bit 2)
  float z0 = 0.f, z1 = 0.f;
  #pragma unroll
  for (int k = 0; k < 16; ++k) {
    const float p = sr[k]*sr[k] + si[k]*si[k];
    z0 += (k & 8) ? -p : p;
    z1 += (k & 4) ? -p : p;
  }
  #pragma unroll
  for (int mm = 1; mm < 64; mm <<= 1) {
    z0 += __shfl_xor(z0, mm, 64);
    z1 += __shfl_xor(z1, mm, 64);
  }

  __shared__ float part[4];
  if (lane == 0) {
    const float mx = fmaxf(z0, z1);
    const float lse = mx + logf(expf(z0 - mx) + expf(z1 - mx));
    const float ly = (yv == 0) ? z0 : z1;
    part[wave] = lse - ly;
  }
  __syncthreads();
  if (threadIdx.x == 0)
    partials[blockIdx.x] = part[0] + part[1] + part[2] + part[3];
}

__global__ void reduce_mean(const float* __restrict__ part, float* __restrict__ out,
                            int n, float scale) {
  const int t = threadIdx.x;
  float s = 0.f;
  for (int i = t; i < n; i += 256) s += part[i];
  #pragma unroll
  for (int mm = 1; mm < 64; mm <<= 1) s += __shfl_xor(s, mm, 64);
  __shared__ float ws[4];
  if ((t & 63) == 0) ws[t >> 6] = s;
  __syncthreads();
  if (t == 0) out[0] = (ws[0] + ws[1] + ws[2] + ws[3]) * scale;
}

} // namespace

extern "C" void kernel_launch(void* const* d_in, const int* in_sizes, int n_in,
                              void* d_out, int out_size, void* d_ws, size_t ws_size,
                              hipStream_t stream) {
  const float* x  = (const float*)d_in[0];
  const int*   y  = (const int*)d_in[1];
  const float* w  = (const float*)d_in[2];
  const float* w1 = (const float*)d_in[3];
  const float* w2 = (const float*)d_in[4];
  float* out = (float*)d_out;

  const int B = in_sizes[0] / 784;      // 8192
  const int nblocks = B / 4;            // 4 waves (batch elems) per 256-thread block

  float* mats     = (float*)d_ws;       // 840 floats
  float* partials = (float*)d_ws + 1024;

  make_mats<<<1, 128, 0, stream>>>(w, w1, w2, mats);
  qsim<<<nblocks, 256, 0, stream>>>(x, y, mats, partials);
  reduce_mean<<<1, 256, 0, stream>>>(partials, out, nblocks, 1.0f / (float)B);
}

// Round 2
// 221.493 us; speedup vs baseline: 1.1888x; 1.1888x over previous
//
#include <hip/hip_runtime.h>

// CCQC quantum-circuit classifier, fused single-kernel state-vector sim.
// State layout: one wave (64 lanes) per batch element; amplitude index
// j = k*64 + lane (k in [0,16)). Wire i (MSB-first) <-> bit b = 9-i of j.
// b in [6,9] -> k-bit (in-lane register pair); b in [0,5] -> lane bit (shfl_xor).
// R1: hoisted all per-k cndmask selects to per-gate lane-invariant coefficients;
//     U0[d] premultiplied into U1[d+1,0] (saves 4 full gates).

namespace {

struct c2 { float r, i; };
struct m2c { c2 a00, a01, a10, a11; };

__device__ __forceinline__ c2 cmul(c2 x, c2 y) { return {x.r*y.r - x.i*y.i, x.r*y.i + x.i*y.r}; }
__device__ __forceinline__ c2 cadd(c2 x, c2 y) { return {x.r + y.r, x.i + y.i}; }
__device__ __forceinline__ m2c mmul(m2c A, m2c B) {
  m2c C;
  C.a00 = cadd(cmul(A.a00, B.a00), cmul(A.a01, B.a10));
  C.a01 = cadd(cmul(A.a00, B.a01), cmul(A.a01, B.a11));
  C.a10 = cadd(cmul(A.a10, B.a00), cmul(A.a11, B.a10));
  C.a11 = cadd(cmul(A.a10, B.a01), cmul(A.a11, B.a11));
  return C;
}
__device__ __forceinline__ m2c mrx(float t) {
  float c = cosf(0.5f * t), s = sinf(0.5f * t);
  return { {c, 0.f}, {0.f, -s}, {0.f, -s}, {c, 0.f} };
}
__device__ __forceinline__ m2c mrz(float t) {
  float c = cosf(0.5f * t), s = sinf(0.5f * t);
  return { {c, -s}, {0.f, 0.f}, {0.f, 0.f}, {c, s} };
}

// Fused gate matrices -> ws. Layout: per layer d (21 matrices of 8 floats):
//   [0..9]  U1[i]  = RX(w[d,i,2]) * RZ(w[d,i,1]) * RX(w[d,i,0]); for i==0,d>0
//                    additionally right-multiplied by U0[d-1] (wire-0 fusion)
//   [10..19] CU[i] = RX(w[d,i,4]) * RZ(w[d,i,3])   (ctrl = (i+r)%10)
//   [20]    U0     = RZ(w2[d]) * RX(w1[d])          (applied only for d==4)
__global__ void make_mats(const float* __restrict__ w, const float* __restrict__ w1,
                          const float* __restrict__ w2, float* __restrict__ mats) {
  int t = threadIdx.x;
  m2c U{}; int idx = -1;
  if (t < 50) {
    int d = t / 10, i = t % 10;
    const float* p = w + (d * 10 + i) * 5;
    U = mmul(mrx(p[2]), mmul(mrz(p[1]), mrx(p[0])));
    if (i == 0 && d > 0) {
      m2c U0 = mmul(mrz(w2[d - 1]), mrx(w1[d - 1]));
      U = mmul(U, U0);   // state <- U1 * (U0 * state)
    }
    idx = d * 21 + i;
  } else if (t < 100) {
    int s = t - 50; int d = s / 10, i = s % 10;
    const float* p = w + (d * 10 + i) * 5;
    U = mmul(mrx(p[4]), mrz(p[3]));
    idx = d * 21 + 10 + i;
  } else if (t < 105) {
    int d = t - 100;
    U = mmul(mrz(w2[d]), mrx(w1[d]));
    idx = d * 21 + 20;
  }
  if (idx >= 0) {
    float* o = mats + idx * 8;
    o[0] = U.a00.r; o[1] = U.a00.i; o[2] = U.a01.r; o[3] = U.a01.i;
    o[4] = U.a10.r; o[5] = U.a10.i; o[6] = U.a11.r; o[7] = U.a11.i;
  }
}

struct Mat8 { float u00r, u00i, u01r, u01i, u10r, u10i, u11r, u11i; };

__device__ __forceinline__ Mat8 ldmat(const float* __restrict__ mats, int idx) {
  const float4* p = reinterpret_cast<const float4*>(mats + idx * 8);
  float4 a = p[0], b = p[1];
  return {a.x, a.y, a.z, a.w, b.x, b.y, b.z, b.w};
}

// Single-qubit gate, target bit is a k-bit (kb = b-6). 16 VALU ops/pair.
__device__ __forceinline__ void ap1q_local(float (&sr)[16], float (&si)[16], const int kb,
                                           const Mat8 m) {
  const int tm = 1 << kb;
  #pragma unroll
  for (int k0 = 0; k0 < 16; ++k0) {
    if (k0 & tm) continue;
    const int k1 = k0 | tm;
    const float ar = sr[k0], ai = si[k0], br = sr[k1], bi = si[k1];
    sr[k0] = m.u00r*ar - m.u00i*ai + m.u01r*br - m.u01i*bi;
    si[k0] = m.u00r*ai + m.u00i*ar + m.u01r*bi + m.u01i*br;
    sr[k1] = m.u10r*ar - m.u10i*ai + m.u11r*br - m.u11i*bi;
    si[k1] = m.u10r*ai + m.u10i*ar + m.u11r*bi + m.u11i*br;
  }
}

// Single-qubit gate, target bit is a lane bit (lm = 1<<b).
// Hoisted: new = cA*own + cB*partner, cA/cB lane-invariant per gate.
// 8 VALU ops + 2 shuffles per k, zero per-k selects.
__device__ __forceinline__ void ap1q_xlane(float (&sr)[16], float (&si)[16],
                                           const int lane, const int lm, const Mat8 m) {
  const bool hi = (lane & lm) != 0;
  const float cAr = hi ? m.u11r : m.u00r, cAi = hi ? m.u11i : m.u00i;
  const float cBr = hi ? m.u10r : m.u01r, cBi = hi ? m.u10i : m.u01i;
  #pragma unroll
  for (int k = 0; k < 16; ++k) {
    const float pr = __shfl_xor(sr[k], lm, 64);
    const float pi = __shfl_xor(si[k], lm, 64);
    const float vr = sr[k], vi = si[k];
    sr[k] = cAr*vr - cAi*vi + cBr*pr - cBi*pi;
    si[k] = cAr*vi + cAi*vr + cBr*pi + cBi*pr;
  }
}

// Controlled gate, target bit is a k-bit (kb = bt-6); ctrl bit bc (j-bit index).
__device__ __forceinline__ void apc_local(float (&sr)[16], float (&si)[16],
                                          const int lane, const int bc, const int kb,
                                          const Mat8 m) {
  const int tm = 1 << kb;
  if (bc >= 6) {
    const int cm = 1 << (bc - 6);
    #pragma unroll
    for (int k0 = 0; k0 < 16; ++k0) {
      if ((k0 & tm) || !(k0 & cm)) continue;
      const int k1 = k0 | tm;
      const float ar = sr[k0], ai = si[k0], br = sr[k1], bi = si[k1];
      sr[k0] = m.u00r*ar - m.u00i*ai + m.u01r*br - m.u01i*bi;
      si[k0] = m.u00r*ai + m.u00i*ar + m.u01r*bi + m.u01i*br;
      sr[k1] = m.u10r*ar - m.u10i*ai + m.u11r*br - m.u11i*bi;
      si[k1] = m.u10r*ai + m.u10i*ar + m.u11r*bi + m.u11i*br;
    }
  } else {
    // ctrl is a lane bit: fold control into the matrix once (M or I per lane).
    const bool cl = ((lane >> bc) & 1) != 0;
    Mat8 mm;
    mm.u00r = cl ? m.u00r : 1.f; mm.u00i = cl ? m.u00i : 0.f;
    mm.u01r = cl ? m.u01r : 0.f; mm.u01i = cl ? m.u01i : 0.f;
    mm.u10r = cl ? m.u10r : 0.f; mm.u10i = cl ? m.u10i : 0.f;
    mm.u11r = cl ? m.u11r : 1.f; mm.u11i = cl ? m.u11i : 0.f;
    ap1q_local(sr, si, kb, mm);
  }
}

// Controlled gate, target bit is a lane bit (lm = 1<<bt); ctrl bit bc.
__device__ __forceinline__ void apc_xlane(float (&sr)[16], float (&si)[16],
                                          const int lane, const int bc, const int lm,
                                          const Mat8 m) {
  const bool hi = (lane & lm) != 0;
  float cAr = hi ? m.u11r : m.u00r, cAi = hi ? m.u11i : m.u00i;
  float cBr = hi ? m.u10r : m.u01r, cBi = hi ? m.u10i : m.u01i;
  if (bc >= 6) {
    const int cm = 1 << (bc - 6);
    #pragma unroll
    for (int k = 0; k < 16; ++k) {
      if (!(k & cm)) continue;   // ctrl bit lives in k: only these amps touched
      const float pr = __shfl_xor(sr[k], lm, 64);
      const float pi = __shfl_xor(si[k], lm, 64);
      const float vr = sr[k], vi = si[k];
      sr[k] = cAr*vr - cAi*vi + cBr*pr - cBi*pi;
      si[k] = cAr*vi + cAi*vr + cBr*pi + cBi*pr;
    }
  } else {
    // ctrl is a lane bit (partner lane shares it): fold into coefficients once.
    const bool cl = ((lane >> bc) & 1) != 0;
    cAr = cl ? cAr : 1.f; cAi = cl ? cAi : 0.f;
    cBr = cl ? cBr : 0.f; cBi = cl ? cBi : 0.f;
    #pragma unroll
    for (int k = 0; k < 16; ++k) {
      const float pr = __shfl_xor(sr[k], lm, 64);
      const float pi = __shfl_xor(si[k], lm, 64);
      const float vr = sr[k], vi = si[k];
      sr[k] = cAr*vr - cAi*vi + cBr*pr - cBi*pi;
      si[k] = cAr*vi + cAi*vr + cBr*pi + cBi*pr;
    }
  }
}

__global__ __launch_bounds__(256) void qsim(const float* __restrict__ x,
                                            const int* __restrict__ y,
                                            const float* __restrict__ mats,
                                            float* __restrict__ partials) {
  const int lane = threadIdx.x & 63;
  const int wave = threadIdx.x >> 6;
  const int b = blockIdx.x * 4 + wave;
  const int yv = y[b];

  float sr[16], si[16];
  float ss = 0.f;
  #pragma unroll
  for (int k = 0; k < 16; ++k) {
    const int j = k * 64 + lane;
    float v = 0.f;
    if (j < 784) v = x[(size_t)b * 784 + j];
    sr[k] = v; si[k] = 0.f; ss += v * v;
  }
  #pragma unroll
  for (int mm = 1; mm < 64; mm <<= 1) ss += __shfl_xor(ss, mm, 64);
  const float rn = rsqrtf(ss);
  #pragma unroll
  for (int k = 0; k < 16; ++k) sr[k] *= rn;

  #pragma unroll
  for (int d = 0; d < 5; ++d) {
    #pragma unroll
    for (int i = 0; i < 10; ++i) {
      const Mat8 m = ldmat(mats, d * 21 + i);
      const int bt = 9 - i;
      if (bt >= 6) ap1q_local(sr, si, bt - 6, m);
      else         ap1q_xlane(sr, si, lane, 1 << bt, m);
    }
    const int r = (d & 1) ? 3 : 1;
    #pragma unroll
    for (int i = 0; i < 10; ++i) {
      const int c = (i + r) % 10;
      const Mat8 m = ldmat(mats, d * 21 + 10 + i);
      const int bc = 9 - c, bt = 9 - i;
      if (bt >= 6) apc_local(sr, si, lane, bc, bt - 6, m);
      else         apc_xlane(sr, si, lane, bc, 1 << bt, m);
    }
    if (d == 4) {  // U0 for d<4 is fused into U1[d+1, 0] by make_mats
      const Mat8 m = ldmat(mats, d * 21 + 20);
      ap1q_local(sr, si, 3, m);   // wire 0 -> j bit 9 -> k bit 3
    }
  }

  // expz for wire 0 (k bit 3) and wire 1 (k bit 2)
  float z0 = 0.f, z1 = 0.f;
  #pragma unroll
  for (int k = 0; k < 16; ++k) {
    const float p = sr[k]*sr[k] + si[k]*si[k];
    z0 += (k & 8) ? -p : p;
    z1 += (k & 4) ? -p : p;
  }
  #pragma unroll
  for (int mm = 1; mm < 64; mm <<= 1) {
    z0 += __shfl_xor(z0, mm, 64);
    z1 += __shfl_xor(z1, mm, 64);
  }

  __shared__ float part[4];
  if (lane == 0) {
    const float mx = fmaxf(z0, z1);
    const float lse = mx + logf(expf(z0 - mx) + expf(z1 - mx));
    const float ly = (yv == 0) ? z0 : z1;
    part[wave] = lse - ly;
  }
  __syncthreads();
  if (threadIdx.x == 0)
    partials[blockIdx.x] = part[0] + part[1] + part[2] + part[3];
}

__global__ void reduce_mean(const float* __restrict__ part, float* __restrict__ out,
                            int n, float scale) {
  const int t = threadIdx.x;
  float s = 0.f;
  for (int i = t; i < n; i += 256) s += part[i];
  #pragma unroll
  for (int mm = 1; mm < 64; mm <<= 1) s += __shfl_xor(s, mm, 64);
  __shared__ float ws[4];
  if ((t & 63) == 0) ws[t >> 6] = s;
  __syncthreads();
  if (t == 0) out[0] = (ws[0] + ws[1] + ws[2] + ws[3]) * scale;
}

} // namespace

extern "C" void kernel_launch(void* const* d_in, const int* in_sizes, int n_in,
                              void* d_out, int out_size, void* d_ws, size_t ws_size,
                              hipStream_t stream) {
  const float* x  = (const float*)d_in[0];
  const int*   y  = (const int*)d_in[1];
  const float* w  = (const float*)d_in[2];
  const float* w1 = (const float*)d_in[3];
  const float* w2 = (const float*)d_in[4];
  float* out = (float*)d_out;

  const int B = in_sizes[0] / 784;      // 8192
  const int nblocks = B / 4;            // 4 waves (batch elems) per 256-thread block

  float* mats     = (float*)d_ws;       // 840 floats
  float* partials = (float*)d_ws + 1024;

  make_mats<<<1, 128, 0, stream>>>(w, w1, w2, mats);
  qsim<<<nblocks, 256, 0, stream>>>(x, y, mats, partials);
  reduce_mean<<<1, 256, 0, stream>>>(partials, out, nblocks, 1.0f / (float)B);
}